// Round 1
// baseline (725.603 us; speedup 1.0000x reference)
//
#include <hip/hip_runtime.h>

// DiffusionMLS: out[row[e]] += w[e] * (u[col[e]] - u[row[e]]), F=32 fp32 feats.
// Round 0: 8 lanes/edge, one float4 of features per lane, scalar f32 atomics.

#define N_FEAT 32

__global__ __launch_bounds__(256) void zero_out_kernel(float* __restrict__ out, int n) {
    int i = blockIdx.x * blockDim.x + threadIdx.x;
    if (i < n) out[i] = 0.0f;
}

__global__ __launch_bounds__(256) void scatter_lap_kernel(
        const float4* __restrict__ u4,     // [N, 8] float4 view of u[N,32]
        const float* __restrict__ w,       // [E]
        const int* __restrict__ row,       // [E]
        const int* __restrict__ col,       // [E]
        float* __restrict__ out,           // [N, 32]
        int n_edges) {
    int tid = blockIdx.x * blockDim.x + threadIdx.x;
    int e  = tid >> 3;   // 8 threads per edge
    int f4 = tid & 7;    // which float4 of the 8 per node
    if (e >= n_edges) return;

    int r = row[e];
    int c = col[e];
    float wt = w[e];

    float4 uc = u4[(size_t)c * 8 + f4];
    float4 ur = u4[(size_t)r * 8 + f4];

    float* o = out + (size_t)r * N_FEAT + f4 * 4;
    atomicAdd(o + 0, wt * (uc.x - ur.x));
    atomicAdd(o + 1, wt * (uc.y - ur.y));
    atomicAdd(o + 2, wt * (uc.z - ur.z));
    atomicAdd(o + 3, wt * (uc.w - ur.w));
}

extern "C" void kernel_launch(void* const* d_in, const int* in_sizes, int n_in,
                              void* d_out, int out_size, void* d_ws, size_t ws_size,
                              hipStream_t stream) {
    const float* u  = (const float*)d_in[0];
    const float* w  = (const float*)d_in[1];
    const int*   ei = (const int*)d_in[2];   // [2, E] int32
    float* out = (float*)d_out;

    const int n_edges = in_sizes[1];
    const int* row = ei;
    const int* col = ei + n_edges;

    // Zero the output (harness poisons it with 0xAA before every launch).
    {
        int n = out_size;
        dim3 block(256), grid((n + 255) / 256);
        zero_out_kernel<<<grid, block, 0, stream>>>(out, n);
    }

    // Scatter-add the weighted Laplacian.
    {
        long long threads_total = (long long)n_edges * 8;
        dim3 block(256), grid((unsigned)((threads_total + 255) / 256));
        scatter_lap_kernel<<<grid, block, 0, stream>>>(
            (const float4*)u, w, row, col, out, n_edges);
    }
}

// Round 2
// 297.103 us; speedup vs baseline: 2.4423x; 2.4423x over previous
//
#include <hip/hip_runtime.h>

// DiffusionMLS: out[row[e]] += w[e]*(u[col[e]] - u[row[e]]), F=32 fp32.
// Round 2: build CSR on the fly (hist + scan + bucket fill), then node-major
// gather with zero f32 atomics. out[n] = sum_e w_e*u[col_e] - (sum_e w_e)*u[n].

#define NFEAT 32
#define SCAN_TILE 2048   // 256 threads * 8 items

// ---------------- CSR build ----------------

__global__ __launch_bounds__(256) void hist_kernel(const int* __restrict__ row,
                                                   int* __restrict__ counts, int E) {
    int e = blockIdx.x * 256 + threadIdx.x;
    if (e < E) atomicAdd(&counts[row[e]], 1);
}

__global__ __launch_bounds__(256) void scan_block_kernel(const int* __restrict__ counts,
                                                         int* __restrict__ offsets,
                                                         int* __restrict__ partials, int N) {
    __shared__ int s[256];
    int tid = threadIdx.x;
    int base = blockIdx.x * SCAN_TILE + tid * 8;
    int v[8];
    int sum = 0;
#pragma unroll
    for (int j = 0; j < 8; ++j) {
        v[j] = (base + j < N) ? counts[base + j] : 0;
        sum += v[j];
    }
    s[tid] = sum;
    __syncthreads();
    for (int off = 1; off < 256; off <<= 1) {
        int t = (tid >= off) ? s[tid - off] : 0;
        __syncthreads();
        s[tid] += t;
        __syncthreads();
    }
    if (tid == 255) partials[blockIdx.x] = s[255];
    int run = s[tid] - sum;  // exclusive prefix of this thread's chunk
#pragma unroll
    for (int j = 0; j < 8; ++j) {
        if (base + j < N) offsets[base + j] = run;
        run += v[j];
    }
}

__global__ void scan_partials_kernel(int* partials, int nparts) {
    if (threadIdx.x == 0 && blockIdx.x == 0) {
        int run = 0;
        for (int i = 0; i < nparts; ++i) {
            int c = partials[i];
            partials[i] = run;
            run += c;
        }
    }
}

__global__ __launch_bounds__(256) void add_offsets_kernel(int* __restrict__ offsets,
                                                          const int* __restrict__ partials,
                                                          int N) {
    int i = blockIdx.x * 256 + threadIdx.x;
    if (i < N) offsets[i] += partials[i >> 11];   // SCAN_TILE = 2048
}

__global__ __launch_bounds__(256) void fill_kernel(const int* __restrict__ row,
                                                   const int* __restrict__ col,
                                                   const float* __restrict__ w,
                                                   const int* __restrict__ offsets,
                                                   int* __restrict__ cursor,
                                                   int* __restrict__ csr_col,
                                                   float* __restrict__ csr_w, int E) {
    int e = blockIdx.x * 256 + threadIdx.x;
    if (e >= E) return;
    int r = row[e];
    int pos = offsets[r] + atomicAdd(&cursor[r], 1);
    csr_col[pos] = col[e];
    csr_w[pos] = w[e];
}

// ---------------- node-major gather ----------------
// One wave per node. 8 edge-slots x 8 lanes; each lane owns one float4 (4 feats).

__global__ __launch_bounds__(256) void node_kernel(const float4* __restrict__ u4,
                                                   const int* __restrict__ offsets,
                                                   const int* __restrict__ counts,
                                                   const int* __restrict__ csr_col,
                                                   const float* __restrict__ csr_w,
                                                   float4* __restrict__ out4, int N) {
    int node = (blockIdx.x * 256 + threadIdx.x) >> 6;
    if (node >= N) return;
    int lane = threadIdx.x & 63;
    int f4 = lane & 7;        // which float4 of the node's 8
    int slot = lane >> 3;     // edge slot 0..7

    int start = offsets[node];
    int cnt = counts[node];

    float4 acc = make_float4(0.f, 0.f, 0.f, 0.f);
    float wsum = 0.f;
    for (int i = start + slot; i < start + cnt; i += 8) {
        int c = csr_col[i];
        float wt = csr_w[i];
        float4 uc = u4[(size_t)c * 8 + f4];
        acc.x += wt * uc.x;
        acc.y += wt * uc.y;
        acc.z += wt * uc.z;
        acc.w += wt * uc.w;
        wsum += wt;
    }
    // reduce across the 8 slots (lane bits 3,4,5)
#pragma unroll
    for (int m = 8; m < 64; m <<= 1) {
        acc.x += __shfl_xor(acc.x, m, 64);
        acc.y += __shfl_xor(acc.y, m, 64);
        acc.z += __shfl_xor(acc.z, m, 64);
        acc.w += __shfl_xor(acc.w, m, 64);
        wsum  += __shfl_xor(wsum,  m, 64);
    }
    if (slot == 0) {
        float4 ur = u4[(size_t)node * 8 + f4];
        float4 o;
        o.x = acc.x - wsum * ur.x;
        o.y = acc.y - wsum * ur.y;
        o.z = acc.z - wsum * ur.z;
        o.w = acc.w - wsum * ur.w;
        out4[(size_t)node * 8 + f4] = o;
    }
}

// ---------------- fallback (round-0 atomic path) ----------------

__global__ __launch_bounds__(256) void zero_out_kernel(float* __restrict__ out, int n) {
    int i = blockIdx.x * blockDim.x + threadIdx.x;
    if (i < n) out[i] = 0.0f;
}

__global__ __launch_bounds__(256) void scatter_lap_kernel(const float4* __restrict__ u4,
                                                          const float* __restrict__ w,
                                                          const int* __restrict__ row,
                                                          const int* __restrict__ col,
                                                          float* __restrict__ out, int n_edges) {
    int tid = blockIdx.x * blockDim.x + threadIdx.x;
    int e = tid >> 3;
    int f4 = tid & 7;
    if (e >= n_edges) return;
    int r = row[e];
    int c = col[e];
    float wt = w[e];
    float4 uc = u4[(size_t)c * 8 + f4];
    float4 ur = u4[(size_t)r * 8 + f4];
    float* o = out + (size_t)r * NFEAT + f4 * 4;
    atomicAdd(o + 0, wt * (uc.x - ur.x));
    atomicAdd(o + 1, wt * (uc.y - ur.y));
    atomicAdd(o + 2, wt * (uc.z - ur.z));
    atomicAdd(o + 3, wt * (uc.w - ur.w));
}

extern "C" void kernel_launch(void* const* d_in, const int* in_sizes, int n_in,
                              void* d_out, int out_size, void* d_ws, size_t ws_size,
                              hipStream_t stream) {
    const float* u = (const float*)d_in[0];
    const float* w = (const float*)d_in[1];
    const int* ei = (const int*)d_in[2];  // [2, E] int32
    float* out = (float*)d_out;

    const int E = in_sizes[1];
    const int N = out_size / NFEAT;
    const int* row = ei;
    const int* col = ei + E;

    // workspace layout (256-B aligned regions)
    const size_t countsOff = 0;
    const size_t countsBytes = ((size_t)N * 4 + 255) & ~(size_t)255;
    const size_t cursorOff = countsOff + countsBytes;
    const size_t partialsOff = cursorOff + countsBytes;
    const size_t partialsBytes = 256;
    const size_t offsetsOff = partialsOff + partialsBytes;
    const size_t csrColOff = offsetsOff + countsBytes;
    const size_t csrColBytes = ((size_t)E * 4 + 255) & ~(size_t)255;
    const size_t csrWOff = csrColOff + csrColBytes;
    const size_t totalWs = csrWOff + csrColBytes;

    if (ws_size < totalWs) {
        // fallback: atomic scatter (round-0 path)
        zero_out_kernel<<<(out_size + 255) / 256, 256, 0, stream>>>(out, out_size);
        long long threads_total = (long long)E * 8;
        scatter_lap_kernel<<<(unsigned)((threads_total + 255) / 256), 256, 0, stream>>>(
            (const float4*)u, w, row, col, out, E);
        return;
    }

    char* ws = (char*)d_ws;
    int* counts = (int*)(ws + countsOff);
    int* cursor = (int*)(ws + cursorOff);
    int* partials = (int*)(ws + partialsOff);
    int* offsets = (int*)(ws + offsetsOff);
    int* csr_col = (int*)(ws + csrColOff);
    float* csr_w = (float*)(ws + csrWOff);

    // zero counts + cursor + partials in one async memset (capture-safe)
    hipMemsetAsync(ws, 0, offsetsOff, stream);

    const int eBlocks = (E + 255) / 256;
    const int nScanBlocks = (N + SCAN_TILE - 1) / SCAN_TILE;

    hist_kernel<<<eBlocks, 256, 0, stream>>>(row, counts, E);
    scan_block_kernel<<<nScanBlocks, 256, 0, stream>>>(counts, offsets, partials, N);
    scan_partials_kernel<<<1, 64, 0, stream>>>(partials, nScanBlocks);
    add_offsets_kernel<<<(N + 255) / 256, 256, 0, stream>>>(offsets, partials, N);
    fill_kernel<<<eBlocks, 256, 0, stream>>>(row, col, w, offsets, cursor, csr_col, csr_w, E);

    // one wave per node, 4 waves per block
    node_kernel<<<(N + 3) / 4, 256, 0, stream>>>((const float4*)u, offsets, counts,
                                                 csr_col, csr_w, (float4*)out, N);
}